// Round 3
// baseline (1148.551 us; speedup 1.0000x reference)
//
#include <hip/hip_runtime.h>
#include <math.h>

// Problem constants (AttentionWriter): B=8,S=1024,M=2048,D=512,H=512,NH=8,Dh=64
#define BB 8
#define SS 1024
#define MM 2048
#define DD 512
#define HH 512
#define NHEAD 8
#define DHEAD 64

typedef __attribute__((ext_vector_type(8))) short short8;
typedef __attribute__((ext_vector_type(4))) float f32x4;

// bf16 split helpers (RNE)
__device__ __forceinline__ unsigned short bf_hi(float x) {
    unsigned int u = __float_as_uint(x);
    return (unsigned short)((u + 0x7FFFu + ((u >> 16) & 1u)) >> 16);
}
__device__ __forceinline__ float bf_f(unsigned short h) {
    return __uint_as_float(((unsigned int)h) << 16);
}

// ---------------------------------------------------------------------------
// f32 GEMM (kept for the precision-sensitive importance path + tiny W_inq)
// C[rows,N] = act(A[rows,K] @ W[K,N] + bias[N]) * rowscale[row/rsdiv]
// ---------------------------------------------------------------------------
__global__ __launch_bounds__(256) void gemm128(
    const float* __restrict__ A, const float* __restrict__ W,
    const float* __restrict__ bias, float* __restrict__ C,
    int K, int N, int act, const float* __restrict__ rowscale, int rsdiv)
{
    __shared__ float As[8][132];
    __shared__ float Bs[8][128];
    const int tid  = threadIdx.x;
    const int row0 = blockIdx.y * 128, col0 = blockIdx.x * 128;
    const int ty = tid >> 4, tx = tid & 15;

    const int arow = tid >> 1,  ak4  = (tid & 1) * 4;
    const int bk   = tid >> 5,  bcol = (tid & 31) * 4;

    const float* Ap = A + (size_t)(row0 + arow) * K + ak4;
    const float* Wp = W + (size_t)bk * N + col0 + bcol;

    float4 aReg = *(const float4*)Ap;
    float4 bReg = *(const float4*)Wp;

    float acc[8][8];
#pragma unroll
    for (int i = 0; i < 8; ++i)
#pragma unroll
        for (int j = 0; j < 8; ++j) acc[i][j] = 0.f;

    for (int k0 = 0; k0 < K; k0 += 8) {
        __syncthreads();
        As[ak4 + 0][arow] = aReg.x;
        As[ak4 + 1][arow] = aReg.y;
        As[ak4 + 2][arow] = aReg.z;
        As[ak4 + 3][arow] = aReg.w;
        *(float4*)&Bs[bk][bcol] = bReg;
        __syncthreads();
        if (k0 + 8 < K) {
            aReg = *(const float4*)(Ap + k0 + 8);
            bReg = *(const float4*)(Wp + (size_t)(k0 + 8) * N);
        }
#pragma unroll
        for (int kk = 0; kk < 8; ++kk) {
            float a[8], b[8];
            *(float4*)&a[0] = *(const float4*)&As[kk][ty * 8];
            *(float4*)&a[4] = *(const float4*)&As[kk][ty * 8 + 4];
            *(float4*)&b[0] = *(const float4*)&Bs[kk][tx * 4];
            *(float4*)&b[4] = *(const float4*)&Bs[kk][64 + tx * 4];
#pragma unroll
            for (int i = 0; i < 8; ++i)
#pragma unroll
                for (int j = 0; j < 8; ++j)
                    acc[i][j] = fmaf(a[i], b[j], acc[i][j]);
        }
    }

#pragma unroll
    for (int i = 0; i < 8; ++i) {
        const int r = row0 + ty * 8 + i;
        const float sc = rowscale ? rowscale[r / rsdiv] : 1.0f;
#pragma unroll
        for (int half = 0; half < 2; ++half) {
            const int c = col0 + half * 64 + tx * 4;
            float4 bv = bias ? *(const float4*)&bias[c] : make_float4(0.f, 0.f, 0.f, 0.f);
            float4 v;
            v.x = acc[i][half * 4 + 0] + bv.x;
            v.y = acc[i][half * 4 + 1] + bv.y;
            v.z = acc[i][half * 4 + 2] + bv.z;
            v.w = acc[i][half * 4 + 3] + bv.w;
            if (act == 1) {
                v.x = fmaxf(v.x, 0.f); v.y = fmaxf(v.y, 0.f);
                v.z = fmaxf(v.z, 0.f); v.w = fmaxf(v.w, 0.f);
            }
            v.x *= sc; v.y *= sc; v.z *= sc; v.w *= sc;
            *(float4*)&C[(size_t)r * N + c] = v;
        }
    }
}

// ---------------------------------------------------------------------------
// split f32 array into bf16 hi/lo arrays (8 elems per thread-task)
// ---------------------------------------------------------------------------
__global__ __launch_bounds__(256) void split_f32(
    const float* __restrict__ x, unsigned short* __restrict__ hi,
    unsigned short* __restrict__ lo, int n8)
{
    const int stride = gridDim.x * 256;
    for (int i = blockIdx.x * 256 + threadIdx.x; i < n8; i += stride) {
        const float4 a = *(const float4*)(x + (size_t)i * 8);
        const float4 b = *(const float4*)(x + (size_t)i * 8 + 4);
        unsigned short h[8], l[8];
        const float v[8] = {a.x, a.y, a.z, a.w, b.x, b.y, b.z, b.w};
#pragma unroll
        for (int e = 0; e < 8; ++e) {
            h[e] = bf_hi(v[e]);
            l[e] = bf_hi(v[e] - bf_f(h[e]));
        }
        uint4 hp, lp;
        hp.x = (unsigned)h[0] | ((unsigned)h[1] << 16);
        hp.y = (unsigned)h[2] | ((unsigned)h[3] << 16);
        hp.z = (unsigned)h[4] | ((unsigned)h[5] << 16);
        hp.w = (unsigned)h[6] | ((unsigned)h[7] << 16);
        lp.x = (unsigned)l[0] | ((unsigned)l[1] << 16);
        lp.y = (unsigned)l[2] | ((unsigned)l[3] << 16);
        lp.z = (unsigned)l[4] | ((unsigned)l[5] << 16);
        lp.w = (unsigned)l[6] | ((unsigned)l[7] << 16);
        *(uint4*)(hi + (size_t)i * 8) = hp;
        *(uint4*)(lo + (size_t)i * 8) = lp;
    }
}

// ---------------------------------------------------------------------------
// transpose + split a [512][512] f32 weight -> Wt_hi/lo [n][k] bf16
// ---------------------------------------------------------------------------
__global__ __launch_bounds__(256) void transpose_split(
    const float* __restrict__ W, unsigned short* __restrict__ Th,
    unsigned short* __restrict__ Tl)
{
    __shared__ float tile[32][33];
    const int tid = threadIdx.x;
    const int n0 = blockIdx.x * 32, k0 = blockIdx.y * 32;
    {
        const int r = tid >> 3, c = (tid & 7) * 4;
        const float4 v = *(const float4*)(W + (size_t)(k0 + r) * 512 + n0 + c);
        tile[r][c + 0] = v.x; tile[r][c + 1] = v.y;
        tile[r][c + 2] = v.z; tile[r][c + 3] = v.w;
    }
    __syncthreads();
    {
        const int n = tid >> 3, k = (tid & 7) * 4;
        unsigned short h[4], l[4];
#pragma unroll
        for (int e = 0; e < 4; ++e) {
            const float x = tile[k + e][n];
            h[e] = bf_hi(x);
            l[e] = bf_hi(x - bf_f(h[e]));
        }
        uint2 hp, lp;
        hp.x = (unsigned)h[0] | ((unsigned)h[1] << 16);
        hp.y = (unsigned)h[2] | ((unsigned)h[3] << 16);
        lp.x = (unsigned)l[0] | ((unsigned)l[1] << 16);
        lp.y = (unsigned)l[2] | ((unsigned)l[3] << 16);
        *(uint2*)(Th + (size_t)(n0 + n) * 512 + k0 + k) = hp;
        *(uint2*)(Tl + (size_t)(n0 + n) * 512 + k0 + k) = lp;
    }
}

// fused bias for Q: out[n] = b_in @ Wq + bq
__global__ __launch_bounds__(256) void bias_fuse(
    const float* __restrict__ b_in, const float* __restrict__ Wq,
    const float* __restrict__ bq, float* __restrict__ out)
{
    const int n = blockIdx.x * 256 + threadIdx.x;
    float a = bq[n];
    for (int k = 0; k < 512; ++k) a = fmaf(b_in[k], Wq[(size_t)k * 512 + n], a);
    out[n] = a;
}

// ---------------------------------------------------------------------------
// Split-bf16 MFMA GEMM: C[rows,N] = (Ah+Al)[rows,K] @ (Bh+Bl)^T[K,N] + bias,
// optionally * rowscale[row/rsdiv].  B given TRANSPOSED: Bt[n][k].
// 3-term: AhBh + AhBl + AlBh (AlBl dropped, ~2^-18 rel).
// Tile 128x128, BK=64, 4 waves (2x2), 4x4 C-frags of 16x16x32 per wave.
// LDS rows [r][64] bf16, 16B-frag XOR swizzle f_phys = f ^ (r&7).
// ---------------------------------------------------------------------------
__global__ __launch_bounds__(256, 2) void gemm_mfma(
    const unsigned short* __restrict__ Ah, const unsigned short* __restrict__ Al,
    const unsigned short* __restrict__ Bh, const unsigned short* __restrict__ Bl,
    const float* __restrict__ bias, float* __restrict__ C,
    int K, int N, const float* __restrict__ rowscale, int rsdiv)
{
    __shared__ unsigned short sm[32768];   // 64KB: A_h | A_l | B_h | B_l
    unsigned short* sAh = sm;
    unsigned short* sAl = sm + 8192;
    unsigned short* sBh = sm + 16384;
    unsigned short* sBl = sm + 24576;
    const int tid = threadIdx.x, lane = tid & 63;
    const int wid = tid >> 6, wm = wid >> 1, wn = wid & 1;
    const int m0 = blockIdx.y * 128, n0 = blockIdx.x * 128;

    f32x4 acc[4][4];
#pragma unroll
    for (int i = 0; i < 4; ++i)
#pragma unroll
        for (int j = 0; j < 4; ++j)
#pragma unroll
            for (int r = 0; r < 4; ++r) acc[i][j][r] = 0.f;

    int srow[4], sf[4], soff[4];
#pragma unroll
    for (int it = 0; it < 4; ++it) {
        const int s = tid + 256 * it;
        srow[it] = s >> 3;
        sf[it] = s & 7;
        soff[it] = srow[it] * 64 + ((sf[it] ^ (srow[it] & 7)) << 3);
    }

    uint4 rAh[4], rAl[4], rBh[4], rBl[4];
#pragma unroll
    for (int it = 0; it < 4; ++it) {
        const size_t ao = (size_t)(m0 + srow[it]) * K + sf[it] * 8;
        const size_t bo = (size_t)(n0 + srow[it]) * K + sf[it] * 8;
        rAh[it] = *(const uint4*)(Ah + ao); rAl[it] = *(const uint4*)(Al + ao);
        rBh[it] = *(const uint4*)(Bh + bo); rBl[it] = *(const uint4*)(Bl + bo);
    }

    for (int k0 = 0; k0 < K; k0 += 64) {
#pragma unroll
        for (int it = 0; it < 4; ++it) {
            *(uint4*)(sAh + soff[it]) = rAh[it];
            *(uint4*)(sAl + soff[it]) = rAl[it];
            *(uint4*)(sBh + soff[it]) = rBh[it];
            *(uint4*)(sBl + soff[it]) = rBl[it];
        }
        __syncthreads();
        if (k0 + 64 < K) {
#pragma unroll
            for (int it = 0; it < 4; ++it) {
                const size_t ao = (size_t)(m0 + srow[it]) * K + (k0 + 64) + sf[it] * 8;
                const size_t bo = (size_t)(n0 + srow[it]) * K + (k0 + 64) + sf[it] * 8;
                rAh[it] = *(const uint4*)(Ah + ao); rAl[it] = *(const uint4*)(Al + ao);
                rBh[it] = *(const uint4*)(Bh + bo); rBl[it] = *(const uint4*)(Bl + bo);
            }
        }
#pragma unroll
        for (int ks = 0; ks < 2; ++ks) {
            short8 afh[4], afl[4], bfh[4], bfl[4];
#pragma unroll
            for (int i = 0; i < 4; ++i) {
                const int row = wm * 64 + i * 16 + (lane & 15);
                const int off = row * 64 + (((ks * 4 + (lane >> 4)) ^ (row & 7)) << 3);
                afh[i] = *(const short8*)(sAh + off);
                afl[i] = *(const short8*)(sAl + off);
            }
#pragma unroll
            for (int j = 0; j < 4; ++j) {
                const int row = wn * 64 + j * 16 + (lane & 15);
                const int off = row * 64 + (((ks * 4 + (lane >> 4)) ^ (row & 7)) << 3);
                bfh[j] = *(const short8*)(sBh + off);
                bfl[j] = *(const short8*)(sBl + off);
            }
#pragma unroll
            for (int i = 0; i < 4; ++i)
#pragma unroll
                for (int j = 0; j < 4; ++j) {
                    acc[i][j] = __builtin_amdgcn_mfma_f32_16x16x32_bf16(afh[i], bfh[j], acc[i][j], 0, 0, 0);
                    acc[i][j] = __builtin_amdgcn_mfma_f32_16x16x32_bf16(afh[i], bfl[j], acc[i][j], 0, 0, 0);
                    acc[i][j] = __builtin_amdgcn_mfma_f32_16x16x32_bf16(afl[i], bfh[j], acc[i][j], 0, 0, 0);
                }
        }
        __syncthreads();
    }

#pragma unroll
    for (int j = 0; j < 4; ++j) {
        const int col = n0 + wn * 64 + j * 16 + (lane & 15);
        const float bj = bias ? bias[col] : 0.f;
#pragma unroll
        for (int i = 0; i < 4; ++i) {
#pragma unroll
            for (int r = 0; r < 4; ++r) {
                const int row = m0 + wm * 64 + i * 16 + (lane >> 4) * 4 + r;
                float v = acc[i][j][r] + bj;
                if (rowscale) v *= rowscale[row / rsdiv];
                C[(size_t)row * N + col] = v;
            }
        }
    }
}

// ---------------------------------------------------------------------------
// Flash attention (f32, unchanged from R2)
// ---------------------------------------------------------------------------
#define LDS_KT 8192
#define LDS_VS 12288

#define LOAD_KV(t)                                                              \
    {                                                                           \
        const float* Kc = Kg + (size_t)((t) * 64) * HH;                         \
        const float* Vc = Vg + (size_t)((t) * 64) * HH;                         \
        _Pragma("unroll")                                                       \
        for (int r = 0; r < 4; ++r)                                             \
            kf[r] = *(const float4*)(Kc + (size_t)(ty * 4 + r) * HH + tx * 4);  \
        _Pragma("unroll")                                                       \
        for (int r = 0; r < 4; ++r)                                             \
            vf[r] = *(const float4*)(Vc + (size_t)(ty + 16 * r) * HH + tx * 4); \
    }

#define WRITE_KV()                                                              \
    {                                                                           \
        const int fk = (ty ^ tx) << 2;                                          \
        _Pragma("unroll")                                                       \
        for (int c = 0; c < 4; ++c) {                                           \
            float4 w;                                                           \
            w.x = (&kf[0].x)[c]; w.y = (&kf[1].x)[c];                           \
            w.z = (&kf[2].x)[c]; w.w = (&kf[3].x)[c];                           \
            *(float4*)&lds[LDS_KT + (4 * tx + c) * 64 + fk] = w;                \
        }                                                                       \
        _Pragma("unroll")                                                       \
        for (int r = 0; r < 4; ++r)                                             \
            *(float4*)&lds[LDS_VS + (ty + 16 * r) * 64 + tx * 4] = vf[r];       \
    }

__global__ __launch_bounds__(256) void attn_kernel(
    const float* __restrict__ qh, const float* __restrict__ kh,
    const float* __restrict__ vh, float* __restrict__ outp)
{
    __shared__ float lds[16384];  // 64KB
    const int tid = threadIdx.x;
    const int ty = tid >> 4, tx = tid & 15;
    const int mt = blockIdx.x, h = blockIdx.y, b = blockIdx.z;
    const int m0 = mt * 128;

    const float* Qg = qh + ((size_t)(b * MM + m0)) * HH + h * DHEAD;
    const float* Kg = kh + ((size_t)b * SS) * HH + h * DHEAD;
    const float* Vg = vh + ((size_t)b * SS) * HH + h * DHEAD;

#pragma unroll
    for (int rr = 0; rr < 2; ++rr) {
        const int task = tid + rr * 256;
        const int qb = task >> 4;
        const int db = task & 15;
        float4 r0 = *(const float4*)(Qg + (size_t)(qb * 4 + 0) * HH + db * 4);
        float4 r1 = *(const float4*)(Qg + (size_t)(qb * 4 + 1) * HH + db * 4);
        float4 r2 = *(const float4*)(Qg + (size_t)(qb * 4 + 2) * HH + db * 4);
        float4 r3 = *(const float4*)(Qg + (size_t)(qb * 4 + 3) * HH + db * 4);
        const int fq = (qb ^ db) << 2;
#pragma unroll
        for (int c = 0; c < 4; ++c) {
            float4 w;
            w.x = (&r0.x)[c]; w.y = (&r1.x)[c]; w.z = (&r2.x)[c]; w.w = (&r3.x)[c];
            *(float4*)&lds[(db * 4 + c) * 128 + fq] = w;
        }
    }

    float4 kf[4], vf[4];
    LOAD_KV(0);
    WRITE_KV();

    float oacc[8][4];
    float mrun[8], lrun[8];
#pragma unroll
    for (int i = 0; i < 8; ++i) {
        mrun[i] = -1e30f; lrun[i] = 0.f;
#pragma unroll
        for (int c = 0; c < 4; ++c) oacc[i][c] = 0.f;
    }

    for (int t = 0; t < SS / 64; ++t) {
        __syncthreads();
        if (t < SS / 64 - 1) LOAD_KV(t + 1);

        float s[8][4];
#pragma unroll
        for (int i = 0; i < 8; ++i)
#pragma unroll
            for (int j = 0; j < 4; ++j) s[i][j] = 0.f;

        for (int kk4 = 0; kk4 < 16; ++kk4) {
            const int sw = kk4 & 15;
#pragma unroll
            for (int c = 0; c < 4; ++c) {
                const int kk = kk4 * 4 + c;
                const float4 a0 = *(const float4*)&lds[kk * 128 + (((2 * ty) ^ sw) << 2)];
                const float4 a1 = *(const float4*)&lds[kk * 128 + (((2 * ty + 1) ^ sw) << 2)];
                const float4 b0 = *(const float4*)&lds[LDS_KT + kk * 64 + ((tx ^ sw) << 2)];
#define FMA4(si, av)                              \
    si[0] = fmaf(av, b0.x, si[0]);                \
    si[1] = fmaf(av, b0.y, si[1]);                \
    si[2] = fmaf(av, b0.z, si[2]);                \
    si[3] = fmaf(av, b0.w, si[3]);
                FMA4(s[0], a0.x) FMA4(s[1], a0.y) FMA4(s[2], a0.z) FMA4(s[3], a0.w)
                FMA4(s[4], a1.x) FMA4(s[5], a1.y) FMA4(s[6], a1.z) FMA4(s[7], a1.w)
#undef FMA4
            }
        }

#pragma unroll
        for (int i = 0; i < 8; ++i) {
            s[i][0] *= 0.125f; s[i][1] *= 0.125f; s[i][2] *= 0.125f; s[i][3] *= 0.125f;
            float mx = fmaxf(fmaxf(s[i][0], s[i][1]), fmaxf(s[i][2], s[i][3]));
#pragma unroll
            for (int msk = 1; msk < 16; msk <<= 1) mx = fmaxf(mx, __shfl_xor(mx, msk));
            const float nm = fmaxf(mrun[i], mx);
            const float sc = __expf(mrun[i] - nm);
            mrun[i] = nm;
            float p0 = __expf(s[i][0] - nm), p1 = __expf(s[i][1] - nm);
            float p2 = __expf(s[i][2] - nm), p3 = __expf(s[i][3] - nm);
            s[i][0] = p0; s[i][1] = p1; s[i][2] = p2; s[i][3] = p3;
            float ps = p0 + p1 + p2 + p3;
#pragma unroll
            for (int msk = 1; msk < 16; msk <<= 1) ps += __shfl_xor(ps, msk);
            lrun[i] = lrun[i] * sc + ps;
            oacc[i][0] *= sc; oacc[i][1] *= sc; oacc[i][2] *= sc; oacc[i][3] *= sc;
        }
        __syncthreads();
#pragma unroll
        for (int half = 0; half < 2; ++half) {
            if (half) __syncthreads();
            if ((tx >> 3) == half) {
                const int txl = tx & 7;
#pragma unroll
                for (int jj = 0; jj < 4; ++jj) {
                    const int jh = 4 * txl + jj;
                    const float4 w0 = make_float4(s[0][jj], s[1][jj], s[2][jj], s[3][jj]);
                    const float4 w1 = make_float4(s[4][jj], s[5][jj], s[6][jj], s[7][jj]);
                    *(float4*)&lds[LDS_KT + jh * 128 + (((2 * ty) ^ txl) << 2)] = w0;
                    *(float4*)&lds[LDS_KT + jh * 128 + (((2 * ty + 1) ^ txl) << 2)] = w1;
                }
            }
            __syncthreads();
#pragma unroll 4
            for (int jl = 0; jl < 32; ++jl) {
                const int swp = (jl >> 2) & 7;
                const float4 a0 = *(const float4*)&lds[LDS_KT + jl * 128 + (((2 * ty) ^ swp) << 2)];
                const float4 a1 = *(const float4*)&lds[LDS_KT + jl * 128 + (((2 * ty + 1) ^ swp) << 2)];
                const float4 b0 = *(const float4*)&lds[LDS_VS + (half * 32 + jl) * 64 + tx * 4];
#define FMA4(oi, av)                              \
    oi[0] = fmaf(av, b0.x, oi[0]);                \
    oi[1] = fmaf(av, b0.y, oi[1]);                \
    oi[2] = fmaf(av, b0.z, oi[2]);                \
    oi[3] = fmaf(av, b0.w, oi[3]);
                FMA4(oacc[0], a0.x) FMA4(oacc[1], a0.y) FMA4(oacc[2], a0.z) FMA4(oacc[3], a0.w)
                FMA4(oacc[4], a1.x) FMA4(oacc[5], a1.y) FMA4(oacc[6], a1.z) FMA4(oacc[7], a1.w)
#undef FMA4
            }
        }

        __syncthreads();
        if (t < SS / 64 - 1) WRITE_KV();
    }

#pragma unroll
    for (int i = 0; i < 8; ++i) {
        const float inv = 1.0f / lrun[i];
        float4 v;
        v.x = oacc[i][0] * inv; v.y = oacc[i][1] * inv;
        v.z = oacc[i][2] * inv; v.w = oacc[i][3] * inv;
        *(float4*)(outp + ((size_t)(b * MM + m0 + 8 * ty + i)) * HH + h * DHEAD + tx * 4) = v;
    }
}

// imp[row] = sigmoid(dot(h1[row,0:256], Wi2) + bi2); one wave per row
__global__ __launch_bounds__(256) void imp_kernel(
    const float* __restrict__ h1, const float* __restrict__ Wi2,
    const float* __restrict__ bi2, float* __restrict__ imp)
{
    const int wv = threadIdx.x >> 6, lane = threadIdx.x & 63;
    const int row = blockIdx.x * 4 + wv;
    const float4 hv = *(const float4*)(h1 + (size_t)row * 256 + lane * 4);
    const float4 wvv = *(const float4*)(Wi2 + lane * 4);
    float s = hv.x * wvv.x + hv.y * wvv.y + hv.z * wvv.z + hv.w * wvv.w;
#pragma unroll
    for (int m = 1; m < 64; m <<= 1) s += __shfl_xor(s, m);
    if (lane == 0) imp[row] = 1.0f / (1.0f + expf(-(s + bi2[0])));
}

// per batch: mean(imp), last index with imp>0.5, exists
__global__ __launch_bounds__(256) void impstats_kernel(
    const float* __restrict__ imp, float* __restrict__ imp_mean,
    int* __restrict__ s_star, int* __restrict__ exists)
{
    const int b = blockIdx.x, tid = threadIdx.x;
    float sum = 0.f; int last = -1;
    for (int s = tid; s < SS; s += 256) {
        const float v = imp[b * SS + s];
        sum += v;
        if (v > 0.5f) last = s;
    }
#pragma unroll
    for (int m = 1; m < 64; m <<= 1) {
        sum += __shfl_xor(sum, m);
        last = max(last, __shfl_xor(last, m));
    }
    __shared__ float ssum[4]; __shared__ int slast[4];
    if ((tid & 63) == 0) { ssum[tid >> 6] = sum; slast[tid >> 6] = last; }
    __syncthreads();
    if (tid == 0) {
        const float t = ssum[0] + ssum[1] + ssum[2] + ssum[3];
        const int ml = max(max(slast[0], slast[1]), max(slast[2], slast[3]));
        imp_mean[b] = t / (float)SS;
        exists[b] = (ml >= 0) ? 1 : 0;
        s_star[b] = (ml >= 0) ? ml : (SS - 1);
    }
}

// rowmean over H of write_weights; one wave per row
__global__ __launch_bounds__(256) void rowmean_kernel(
    const float* __restrict__ ww, float* __restrict__ rm)
{
    const int wv = threadIdx.x >> 6, lane = threadIdx.x & 63;
    const int row = blockIdx.x * 4 + wv;
    const float* p = ww + (size_t)row * HH + lane * 8;
    const float4 v0 = *(const float4*)p;
    const float4 v1 = *(const float4*)(p + 4);
    float s = v0.x + v0.y + v0.z + v0.w + v1.x + v1.y + v1.z + v1.w;
#pragma unroll
    for (int m = 1; m < 64; m <<= 1) s += __shfl_xor(s, m);
    if (lane == 0) rm[row] = s * (1.0f / (float)HH);
}

// per batch: first-occurrence argmax over M rowmeans
__global__ __launch_bounds__(256) void argmax_kernel(
    const float* __restrict__ rm, int* __restrict__ pos)
{
    const int b = blockIdx.x, tid = threadIdx.x;
    float best = -3.0e38f; int bidx = 1 << 30;
    for (int m = tid; m < MM; m += 256) {
        const float v = rm[b * MM + m];
        if (v > best || (v == best && m < bidx)) { best = v; bidx = m; }
    }
#pragma unroll
    for (int msk = 1; msk < 64; msk <<= 1) {
        const float ov = __shfl_xor(best, msk);
        const int oi = __shfl_xor(bidx, msk);
        if (ov > best || (ov == best && oi < bidx)) { best = ov; bidx = oi; }
    }
    __shared__ float sv[4]; __shared__ int si[4];
    if ((tid & 63) == 0) { sv[tid >> 6] = best; si[tid >> 6] = bidx; }
    __syncthreads();
    if (tid == 0) {
        for (int w = 1; w < 4; ++w)
            if (sv[w] > best || (sv[w] == best && si[w] < bidx)) { best = sv[w]; bidx = si[w]; }
        pos[b] = bidx;
    }
}

// per batch: upd = tanh(relu([old,sel]@Wu1+bu1)@Wu2+bu2); write updated row
__global__ __launch_bounds__(256) void update_kernel(
    const float* __restrict__ mb, const float* __restrict__ ni,
    const float* __restrict__ Wu1, const float* __restrict__ bu1,
    const float* __restrict__ Wu2, const float* __restrict__ bu2,
    const float* __restrict__ wwp, const int* __restrict__ pos,
    const int* __restrict__ s_star, const int* __restrict__ exists,
    float* __restrict__ outu)
{
    const int b = blockIdx.x, tid = threadIdx.x;
    __shared__ float comb[2 * DD];
    __shared__ float hu[HH];
    const int p = pos[b], ss = s_star[b], ex = exists[b];
    const float* oldp = mb + ((size_t)(b * MM + p)) * DD;
    const float* selp = ni + ((size_t)(b * SS + ss)) * DD;
    for (int i = tid; i < DD; i += 256) { comb[i] = oldp[i]; comb[DD + i] = selp[i]; }
    __syncthreads();
#pragma unroll
    for (int t = 0; t < 2; ++t) {
        const int n = tid + t * 256;
        float a = bu1[n];
        for (int k = 0; k < 2 * DD; ++k) a = fmaf(comb[k], Wu1[(size_t)k * HH + n], a);
        hu[n] = fmaxf(a, 0.f);
    }
    __syncthreads();
#pragma unroll
    for (int t = 0; t < 2; ++t) {
        const int n = tid + t * 256;
        float a = bu2[n];
        for (int k = 0; k < HH; ++k) a = fmaf(hu[k], Wu2[(size_t)k * HH + n], a);
        const float upd = tanhf(a);
        const float wwv = wwp[((size_t)(b * MM + p)) * HH + n];
        const float ov = oldp[n];
        outu[((size_t)(b * MM + p)) * DD + n] = ex ? fmaf(upd, wwv, ov) : ov;
    }
}

extern "C" void kernel_launch(void* const* d_in, const int* in_sizes, int n_in,
                              void* d_out, int out_size, void* d_ws, size_t ws_size,
                              hipStream_t stream)
{
    const float* new_info    = (const float*)d_in[0];
    const float* memory_bank = (const float*)d_in[1];
    const float* W_in = (const float*)d_in[2];  const float* b_in = (const float*)d_in[3];
    const float* Wq   = (const float*)d_in[4];  const float* bq   = (const float*)d_in[5];
    const float* Wk   = (const float*)d_in[6];  const float* bk   = (const float*)d_in[7];
    const float* Wv   = (const float*)d_in[8];  const float* bv   = (const float*)d_in[9];
    const float* Wo   = (const float*)d_in[10]; const float* bo   = (const float*)d_in[11];
    const float* Wi1  = (const float*)d_in[12]; const float* bi1  = (const float*)d_in[13];
    const float* Wi2  = (const float*)d_in[14]; const float* bi2  = (const float*)d_in[15];
    const float* Wu1  = (const float*)d_in[16]; const float* bu1  = (const float*)d_in[17];
    const float* Wu2  = (const float*)d_in[18]; const float* bu2  = (const float*)d_in[19];

    float* out = (float*)d_out;
    float* out_updated = out;                               // B*M*D
    float* out_ww      = out + (size_t)BB * MM * HH;        // B*M*H
    float* out_imp     = out + 2 * (size_t)BB * MM * HH;    // B*S

    // workspace layout (f32 units), ~139.7 MB total
    float* ws = (float*)d_ws;
    float* info_proj = ws;                                   // 4,194,304
    float* khb       = info_proj + 4194304;                  // 4,194,304
    float* vhb       = khb + 4194304;                        // 4,194,304
    float* qhb       = vhb + 4194304;                        // 8,388,608 (hidden1 aliases)
    float* mb_region = qhb + 8388608;                        // 8,388,608
    float* ip_region = mb_region + 8388608;                  // 4,194,304
    float* wt_region = ip_region + 4194304;                  // 1,048,576
    float* winq      = wt_region + 1048576;                  // 262,144
    float* bq_eff    = winq + 262144;                        // 512
    float* rowmeanv  = bq_eff + 512;                         // 16,384
    float* imp_mean  = rowmeanv + 16384;                     // 8
    int*   ipos      = (int*)(imp_mean + BB);
    int*   istar     = ipos + BB;
    int*   iexists   = istar + BB;

    float* hidden1 = qhb;  // B*S*256, dead before Q-GEMM writes qhb

    unsigned short* mbh = (unsigned short*)mb_region;        // 8,388,608 u16
    unsigned short* mbl = mbh + 8388608;
    unsigned short* iph = (unsigned short*)ip_region;        // 4,194,304 u16
    unsigned short* ipl = iph + 4194304;
    unsigned short* wtq_h = (unsigned short*)wt_region;      // 8 x 262,144 u16
    unsigned short* wtq_l = wtq_h + 262144;
    unsigned short* wtk_h = wtq_l + 262144;
    unsigned short* wtk_l = wtk_h + 262144;
    unsigned short* wtv_h = wtk_l + 262144;
    unsigned short* wtv_l = wtv_h + 262144;
    unsigned short* wto_h = wtv_l + 262144;
    unsigned short* wto_l = wto_h + 262144;
    // attn-out split aliases dead khb/vhb (each exactly 8,388,608 u16)
    unsigned short* aoh = (unsigned short*)khb;
    unsigned short* aol = (unsigned short*)vhb;

    const dim3 blk(256);

    hipMemcpyAsync(out_updated, memory_bank,
                   (size_t)BB * MM * DD * sizeof(float),
                   hipMemcpyDeviceToDevice, stream);

    // ---- weight prep: W_inq = W_in@Wq (fused), bias', transpose+split all
    gemm128<<<dim3(4, 4), blk, 0, stream>>>(W_in, Wq, nullptr, winq,
                                            512, 512, 0, nullptr, 1);
    bias_fuse<<<dim3(2), blk, 0, stream>>>(b_in, Wq, bq, bq_eff);
    transpose_split<<<dim3(16, 16), blk, 0, stream>>>(winq, wtq_h, wtq_l);
    transpose_split<<<dim3(16, 16), blk, 0, stream>>>(Wk, wtk_h, wtk_l);
    transpose_split<<<dim3(16, 16), blk, 0, stream>>>(Wv, wtv_h, wtv_l);
    transpose_split<<<dim3(16, 16), blk, 0, stream>>>(Wo, wto_h, wto_l);
    split_f32<<<dim3(2048), blk, 0, stream>>>(memory_bank, mbh, mbl, 1048576);

    // ---- importance path stays f32
    gemm128<<<dim3(4, 64), blk, 0, stream>>>(new_info, W_in, b_in, info_proj,
                                             DD, HH, 0, nullptr, 1);
    gemm128<<<dim3(2, 64), blk, 0, stream>>>(info_proj, Wi1, bi1, hidden1,
                                             HH, HH / 2, 1, nullptr, 1);
    imp_kernel<<<dim3((BB * SS) / 4), blk, 0, stream>>>(hidden1, Wi2, bi2, out_imp);
    impstats_kernel<<<dim3(BB), blk, 0, stream>>>(out_imp, imp_mean, istar, iexists);

    // ---- MFMA GEMMs
    split_f32<<<dim3(2048), blk, 0, stream>>>(info_proj, iph, ipl, 524288);
    gemm_mfma<<<dim3(4, 128), blk, 0, stream>>>(mbh, mbl, wtq_h, wtq_l,
                                                bq_eff, qhb, 512, 512, nullptr, 1);
    gemm_mfma<<<dim3(4, 64), blk, 0, stream>>>(iph, ipl, wtk_h, wtk_l,
                                               bk, khb, 512, 512, nullptr, 1);
    gemm_mfma<<<dim3(4, 64), blk, 0, stream>>>(iph, ipl, wtv_h, wtv_l,
                                               bv, vhb, 512, 512, nullptr, 1);

    attn_kernel<<<dim3(MM / 128, NHEAD, BB), blk, 0, stream>>>(qhb, khb, vhb, qhb);

    split_f32<<<dim3(2048), blk, 0, stream>>>(qhb, aoh, aol, 1048576);
    gemm_mfma<<<dim3(4, 128), blk, 0, stream>>>(aoh, aol, wto_h, wto_l,
                                                bo, out_ww, 512, 512, imp_mean, MM);

    rowmean_kernel<<<dim3((BB * MM) / 4), blk, 0, stream>>>(out_ww, rowmeanv);
    argmax_kernel<<<dim3(BB), blk, 0, stream>>>(rowmeanv, ipos);
    update_kernel<<<dim3(BB), blk, 0, stream>>>(memory_bank, new_info,
                                                Wu1, bu1, Wu2, bu2, out_ww,
                                                ipos, istar, iexists, out_updated);
}

// Round 4
// 642.820 us; speedup vs baseline: 1.7867x; 1.7867x over previous
//
#include <hip/hip_runtime.h>
#include <math.h>

// Problem constants (AttentionWriter): B=8,S=1024,M=2048,D=512,H=512,NH=8,Dh=64
#define BB 8
#define SS 1024
#define MM 2048
#define DD 512
#define HH 512
#define NHEAD 8
#define DHEAD 64

typedef __attribute__((ext_vector_type(8))) short short8;
typedef __attribute__((ext_vector_type(4))) float f32x4;
typedef unsigned short us;

// bf16 split helpers (RNE)
__device__ __forceinline__ us bf_hi(float x) {
    unsigned u = __float_as_uint(x);
    return (us)((u + 0x7FFFu + ((u >> 16) & 1u)) >> 16);
}
__device__ __forceinline__ float bf_f(us h) {
    return __uint_as_float(((unsigned)h) << 16);
}
// split 4 floats -> hi uint2 (4 bf16) + lo uint2 (4 bf16)
__device__ __forceinline__ void split_pack4(float a, float b, float c, float d,
                                            uint2& hp, uint2& lp) {
    us h0 = bf_hi(a), h1 = bf_hi(b), h2 = bf_hi(c), h3 = bf_hi(d);
    hp.x = (unsigned)h0 | ((unsigned)h1 << 16);
    hp.y = (unsigned)h2 | ((unsigned)h3 << 16);
    us l0 = bf_hi(a - bf_f(h0)), l1 = bf_hi(b - bf_f(h1));
    us l2 = bf_hi(c - bf_f(h2)), l3 = bf_hi(d - bf_f(h3));
    lp.x = (unsigned)l0 | ((unsigned)l1 << 16);
    lp.y = (unsigned)l2 | ((unsigned)l3 << 16);
}

// ---------------------------------------------------------------------------
// f32 GEMM (precision-sensitive importance path ONLY)
// ---------------------------------------------------------------------------
__global__ __launch_bounds__(256) void gemm128(
    const float* __restrict__ A, const float* __restrict__ W,
    const float* __restrict__ bias, float* __restrict__ C,
    int K, int N, int act, const float* __restrict__ rowscale, int rsdiv)
{
    __shared__ float As[8][132];
    __shared__ float Bs[8][128];
    const int tid  = threadIdx.x;
    const int row0 = blockIdx.y * 128, col0 = blockIdx.x * 128;
    const int ty = tid >> 4, tx = tid & 15;

    const int arow = tid >> 1,  ak4  = (tid & 1) * 4;
    const int bk   = tid >> 5,  bcol = (tid & 31) * 4;

    const float* Ap = A + (size_t)(row0 + arow) * K + ak4;
    const float* Wp = W + (size_t)bk * N + col0 + bcol;

    float4 aReg = *(const float4*)Ap;
    float4 bReg = *(const float4*)Wp;

    float acc[8][8];
#pragma unroll
    for (int i = 0; i < 8; ++i)
#pragma unroll
        for (int j = 0; j < 8; ++j) acc[i][j] = 0.f;

    for (int k0 = 0; k0 < K; k0 += 8) {
        __syncthreads();
        As[ak4 + 0][arow] = aReg.x;
        As[ak4 + 1][arow] = aReg.y;
        As[ak4 + 2][arow] = aReg.z;
        As[ak4 + 3][arow] = aReg.w;
        *(float4*)&Bs[bk][bcol] = bReg;
        __syncthreads();
        if (k0 + 8 < K) {
            aReg = *(const float4*)(Ap + k0 + 8);
            bReg = *(const float4*)(Wp + (size_t)(k0 + 8) * N);
        }
#pragma unroll
        for (int kk = 0; kk < 8; ++kk) {
            float a[8], b[8];
            *(float4*)&a[0] = *(const float4*)&As[kk][ty * 8];
            *(float4*)&a[4] = *(const float4*)&As[kk][ty * 8 + 4];
            *(float4*)&b[0] = *(const float4*)&Bs[kk][tx * 4];
            *(float4*)&b[4] = *(const float4*)&Bs[kk][64 + tx * 4];
#pragma unroll
            for (int i = 0; i < 8; ++i)
#pragma unroll
                for (int j = 0; j < 8; ++j)
                    acc[i][j] = fmaf(a[i], b[j], acc[i][j]);
        }
    }

#pragma unroll
    for (int i = 0; i < 8; ++i) {
        const int r = row0 + ty * 8 + i;
        const float sc = rowscale ? rowscale[r / rsdiv] : 1.0f;
#pragma unroll
        for (int half = 0; half < 2; ++half) {
            const int c = col0 + half * 64 + tx * 4;
            float4 bv = bias ? *(const float4*)&bias[c] : make_float4(0.f, 0.f, 0.f, 0.f);
            float4 v;
            v.x = acc[i][half * 4 + 0] + bv.x;
            v.y = acc[i][half * 4 + 1] + bv.y;
            v.z = acc[i][half * 4 + 2] + bv.z;
            v.w = acc[i][half * 4 + 3] + bv.w;
            if (act == 1) {
                v.x = fmaxf(v.x, 0.f); v.y = fmaxf(v.y, 0.f);
                v.z = fmaxf(v.z, 0.f); v.w = fmaxf(v.w, 0.f);
            }
            v.x *= sc; v.y *= sc; v.z *= sc; v.w *= sc;
            *(float4*)&C[(size_t)r * N + c] = v;
        }
    }
}

// ---------------------------------------------------------------------------
// batched transpose+split of five [512][512] f32 weights -> [n][k] bf16 hi/lo
// ---------------------------------------------------------------------------
struct TS5 {
    const float* src[5];
    us* dh[5];
    us* dl[5];
};
__global__ __launch_bounds__(256) void transpose_split_batch(TS5 a)
{
    __shared__ float tile[32][33];
    const int tid = threadIdx.x;
    const int n0 = blockIdx.x * 32, k0 = blockIdx.y * 32;
    const int wsel = blockIdx.z;
    const float* W = a.src[wsel];
    {
        const int r = tid >> 3, c = (tid & 7) * 4;
        const float4 v = *(const float4*)(W + (size_t)(k0 + r) * 512 + n0 + c);
        tile[r][c + 0] = v.x; tile[r][c + 1] = v.y;
        tile[r][c + 2] = v.z; tile[r][c + 3] = v.w;
    }
    __syncthreads();
    {
        const int n = tid >> 3, k = (tid & 7) * 4;
        uint2 hp, lp;
        split_pack4(tile[k + 0][n], tile[k + 1][n], tile[k + 2][n], tile[k + 3][n], hp, lp);
        *(uint2*)(a.dh[wsel] + (size_t)(n0 + n) * 512 + k0 + k) = hp;
        *(uint2*)(a.dl[wsel] + (size_t)(n0 + n) * 512 + k0 + k) = lp;
    }
}

// ---------------------------------------------------------------------------
// Split-bf16 MFMA GEMM, f32 A staged+split in-kernel; B pre-split [N][K] bf16.
// C = (Ah+Al)@(Bh+Bl)^T + bias  (3-term), optional rowscale.
// Tile 128x128, BK=64, 4 waves (2x2), 4x4 16x16x32 frags/wave.
// LDS rows [r][64] bf16, 16B-frag XOR swizzle f_phys = f_log ^ (r&7).
// ---------------------------------------------------------------------------
__global__ __launch_bounds__(256) void gemm_mfma(
    const float* __restrict__ A,
    const us* __restrict__ Bh, const us* __restrict__ Bl,
    const float* __restrict__ bias, float* __restrict__ C,
    int K, int N, const float* __restrict__ rowscale, int rsdiv)
{
    __shared__ us sm[32768];   // 64KB: A_h | A_l | B_h | B_l
    us* sAh = sm;
    us* sAl = sm + 8192;
    us* sBh = sm + 16384;
    us* sBl = sm + 24576;
    const int tid = threadIdx.x, lane = tid & 63;
    const int wid = tid >> 6, wm = wid >> 1, wn = wid & 1;
    const int m0 = blockIdx.y * 128, n0 = blockIdx.x * 128;
    const int fr = lane & 15, fq4 = lane >> 4;

    f32x4 acc[4][4];
#pragma unroll
    for (int i = 0; i < 4; ++i)
#pragma unroll
        for (int j = 0; j < 4; ++j)
#pragma unroll
            for (int r = 0; r < 4; ++r) acc[i][j][r] = 0.f;

    // A staging: pass p -> row p*16+ar, k-cols ak..ak+3 (f32)
    const int ar = tid >> 4;
    const int ak = (tid & 15) * 4;
    // B staging (pre-split bf16): 4 slots of 16B frags
    int bsrow[4], bsf[4], bsoff[4];
#pragma unroll
    for (int it = 0; it < 4; ++it) {
        const int s = tid + 256 * it;
        bsrow[it] = s >> 3;
        bsf[it] = s & 7;
        bsoff[it] = bsrow[it] * 64 + ((bsf[it] ^ (bsrow[it] & 7)) << 3);
    }

    float4 aR[8];
    uint4 bhR[4], blR[4];
#pragma unroll
    for (int p = 0; p < 8; ++p)
        aR[p] = *(const float4*)(A + (size_t)(m0 + p * 16 + ar) * K + ak);
#pragma unroll
    for (int it = 0; it < 4; ++it) {
        const size_t bo = (size_t)(n0 + bsrow[it]) * K + bsf[it] * 8;
        bhR[it] = *(const uint4*)(Bh + bo);
        blR[it] = *(const uint4*)(Bl + bo);
    }

    for (int k0 = 0; k0 < K; k0 += 64) {
        __syncthreads();
#pragma unroll
        for (int p = 0; p < 8; ++p) {
            const int r = p * 16 + ar;
            const int aoff = r * 128 + (((ak >> 3) ^ (r & 7)) << 4) + ((tid & 1) << 3);
            uint2 hp, lp;
            split_pack4(aR[p].x, aR[p].y, aR[p].z, aR[p].w, hp, lp);
            *(uint2*)((char*)sAh + aoff) = hp;
            *(uint2*)((char*)sAl + aoff) = lp;
        }
#pragma unroll
        for (int it = 0; it < 4; ++it) {
            *(uint4*)(sBh + bsoff[it]) = bhR[it];
            *(uint4*)(sBl + bsoff[it]) = blR[it];
        }
        __syncthreads();
        if (k0 + 64 < K) {
#pragma unroll
            for (int p = 0; p < 8; ++p)
                aR[p] = *(const float4*)(A + (size_t)(m0 + p * 16 + ar) * K + k0 + 64 + ak);
#pragma unroll
            for (int it = 0; it < 4; ++it) {
                const size_t bo = (size_t)(n0 + bsrow[it]) * K + k0 + 64 + bsf[it] * 8;
                bhR[it] = *(const uint4*)(Bh + bo);
                blR[it] = *(const uint4*)(Bl + bo);
            }
        }
#pragma unroll
        for (int ks = 0; ks < 2; ++ks) {
            short8 afh[4], afl[4], bfh[4], bfl[4];
#pragma unroll
            for (int i = 0; i < 4; ++i) {
                const int row = wm * 64 + i * 16 + fr;
                const int off = row * 128 + (((ks * 4 + fq4) ^ (row & 7)) << 4);
                afh[i] = *(const short8*)((const char*)sAh + off);
                afl[i] = *(const short8*)((const char*)sAl + off);
            }
#pragma unroll
            for (int j = 0; j < 4; ++j) {
                const int row = wn * 64 + j * 16 + fr;
                const int off = row * 128 + (((ks * 4 + fq4) ^ (row & 7)) << 4);
                bfh[j] = *(const short8*)((const char*)sBh + off);
                bfl[j] = *(const short8*)((const char*)sBl + off);
            }
#pragma unroll
            for (int i = 0; i < 4; ++i)
#pragma unroll
                for (int j = 0; j < 4; ++j) {
                    acc[i][j] = __builtin_amdgcn_mfma_f32_16x16x32_bf16(afh[i], bfh[j], acc[i][j], 0, 0, 0);
                    acc[i][j] = __builtin_amdgcn_mfma_f32_16x16x32_bf16(afh[i], bfl[j], acc[i][j], 0, 0, 0);
                    acc[i][j] = __builtin_amdgcn_mfma_f32_16x16x32_bf16(afl[i], bfh[j], acc[i][j], 0, 0, 0);
                }
        }
    }

#pragma unroll
    for (int j = 0; j < 4; ++j) {
        const int col = n0 + wn * 64 + j * 16 + fr;
        const float bj = bias ? bias[col] : 0.f;
#pragma unroll
        for (int i = 0; i < 4; ++i) {
#pragma unroll
            for (int r = 0; r < 4; ++r) {
                const int row = m0 + wm * 64 + i * 16 + fq4 * 4 + r;
                float v = acc[i][j][r] + bj;
                if (rowscale) v *= rowscale[row / rsdiv];
                C[(size_t)row * N + col] = v;
            }
        }
    }
}

// ---------------------------------------------------------------------------
// MFMA flash attention. Per block: 128 q-rows, one (b,h); kv-chunks of 64.
// 4 waves x 32q. Swapped QK^T (K as A, Q^T as B) -> P[q][s] packable as b64.
// 3-term split-bf16 for QK^T and PV. K/Vt/P in LDS (64KB+512B), Q in regs.
// Swizzle: 16B-frag f_phys = f_log ^ (row&7) on all [*][64]-bf16 tiles.
// ---------------------------------------------------------------------------
__global__ __launch_bounds__(256) void attn_mfma(
    const float* __restrict__ qh, const float* __restrict__ kh,
    const float* __restrict__ vh, float* __restrict__ outp)
{
    __shared__ us sm[32768];    // sKh|sKl|sVh|sVl|sPh|sPl
    __shared__ float sSc[128];
    us* sKh = sm;            us* sKl = sm + 4096;
    us* sVh = sm + 8192;     us* sVl = sm + 12288;
    us* sPh = sm + 16384;    us* sPl = sm + 24576;

    const int tid = threadIdx.x, lane = tid & 63, w = tid >> 6;
    const int fr = lane & 15, fq4 = lane >> 4;

    // XCD swizzle: 16 blocks sharing (b,h) land on one XCD (K/V L2 reuse)
    const int wg = blockIdx.x;              // 0..1023
    const int xcd = wg & 7, ix = wg >> 3;
    const int pair = xcd + 8 * (ix >> 4);   // 0..63
    const int mt = ix & 15;
    const int h = pair & 7, b = pair >> 3;
    const int m0 = mt * 128;

    const float* Qg = qh + ((size_t)(b * MM + m0)) * HH + h * DHEAD;
    const float* Kg = kh + ((size_t)b * SS) * HH + h * DHEAD;
    const float* Vg = vh + ((size_t)b * SS) * HH + h * DHEAD;
    float* Og = outp + ((size_t)(b * MM + m0)) * HH + h * DHEAD;

    // ---- Q fragments in registers (pre-scaled by 1/8), hi/lo split
    short8 qfh[2][2], qfl[2][2];   // [fq][ks]
#pragma unroll
    for (int fqi = 0; fqi < 2; ++fqi)
#pragma unroll
        for (int ks = 0; ks < 2; ++ks) {
            const float* qp = Qg + (size_t)(w * 32 + fqi * 16 + fr) * HH + ks * 32 + fq4 * 8;
            const float4 u0 = *(const float4*)qp;
            const float4 u1 = *(const float4*)(qp + 4);
            float v[8] = {u0.x, u0.y, u0.z, u0.w, u1.x, u1.y, u1.z, u1.w};
#pragma unroll
            for (int e = 0; e < 8; ++e) {
                const float x = v[e] * 0.125f;
                const us hb = bf_hi(x);
                qfh[fqi][ks][e] = (short)hb;
                qfl[fqi][ks][e] = (short)bf_hi(x - bf_f(hb));
            }
        }

    // staging indices
    const int kr = tid >> 4;              // K: row-within-16
    const int kc = (tid & 15) * 4;        // K: d4
    const int vs4 = (tid & 15) * 4;       // V: s4
    const int vd4 = (tid >> 4) * 4;       // V: d4
    const int stf = (((tid & 15) >> 1) << 4) + ((tid & 1) << 3); // frag byte part

    float4 kreg[4], vreg[4];
#define LOADKV(t)                                                                   \
    {                                                                               \
        _Pragma("unroll")                                                           \
        for (int p = 0; p < 4; ++p)                                                 \
            kreg[p] = *(const float4*)(Kg + (size_t)((t) * 64 + p * 16 + kr) * HH + kc); \
        _Pragma("unroll")                                                           \
        for (int i = 0; i < 4; ++i)                                                 \
            vreg[i] = *(const float4*)(Vg + (size_t)((t) * 64 + vs4 + i) * HH + vd4); \
    }
#define STOREKV()                                                                   \
    {                                                                               \
        _Pragma("unroll")                                                           \
        for (int p = 0; p < 4; ++p) {                                               \
            const int r = p * 16 + kr;                                              \
            const int off = r * 128 + ((stf ^ ((r & 7) << 4)));                     \
            uint2 hp, lp;                                                           \
            split_pack4(kreg[p].x, kreg[p].y, kreg[p].z, kreg[p].w, hp, lp);        \
            *(uint2*)((char*)sKh + off) = hp;                                       \
            *(uint2*)((char*)sKl + off) = lp;                                       \
        }                                                                           \
        _Pragma("unroll")                                                           \
        for (int dd = 0; dd < 3 + 1; ++dd) {                                        \
            const int d = vd4 + dd;                                                 \
            const int off = d * 128 + ((stf ^ ((d & 7) << 4)));                     \
            uint2 hp, lp;                                                           \
            split_pack4((&vreg[0].x)[dd], (&vreg[1].x)[dd],                         \
                        (&vreg[2].x)[dd], (&vreg[3].x)[dd], hp, lp);                \
            *(uint2*)((char*)sVh + off) = hp;                                       \
            *(uint2*)((char*)sVl + off) = lp;                                       \
        }                                                                           \
    }

    f32x4 oacc[2][4];
#pragma unroll
    for (int i = 0; i < 2; ++i)
#pragma unroll
        for (int j = 0; j < 4; ++j)
#pragma unroll
            for (int r = 0; r < 4; ++r) oacc[i][j][r] = 0.f;
    float mrun[2] = {-1e30f, -1e30f}, lrun[2] = {0.f, 0.f};

    LOADKV(0);
    for (int t = 0; t < SS / 64; ++t) {
        __syncthreads();                 // prev chunk's K/Vt reads done
        STOREKV();
        __syncthreads();                 // staging visible
        if (t < SS / 64 - 1) LOADKV(t + 1);

        // ---- QK^T (swapped): stt[fs][fq] = K-slice x Q^T; C: row=s, col=q
        f32x4 stt[4][2];
#pragma unroll
        for (int fs = 0; fs < 4; ++fs)
#pragma unroll
            for (int fqi = 0; fqi < 2; ++fqi)
#pragma unroll
                for (int r = 0; r < 4; ++r) stt[fs][fqi][r] = 0.f;
#pragma unroll
        for (int ks = 0; ks < 2; ++ks) {
            short8 kfh[4], kfl[4];
#pragma unroll
            for (int fs = 0; fs < 4; ++fs) {
                const int row = fs * 16 + fr;
                const int off = row * 128 + (((ks * 4 + fq4) ^ (row & 7)) << 4);
                kfh[fs] = *(const short8*)((const char*)sKh + off);
                kfl[fs] = *(const short8*)((const char*)sKl + off);
            }
#pragma unroll
            for (int fs = 0; fs < 4; ++fs)
#pragma unroll
                for (int fqi = 0; fqi < 2; ++fqi) {
                    stt[fs][fqi] = __builtin_amdgcn_mfma_f32_16x16x32_bf16(kfh[fs], qfh[fqi][ks], stt[fs][fqi], 0, 0, 0);
                    stt[fs][fqi] = __builtin_amdgcn_mfma_f32_16x16x32_bf16(kfh[fs], qfl[fqi][ks], stt[fs][fqi], 0, 0, 0);
                    stt[fs][fqi] = __builtin_amdgcn_mfma_f32_16x16x32_bf16(kfl[fs], qfh[fqi][ks], stt[fs][fqi], 0, 0, 0);
                }
        }

        // ---- online softmax (per q = fqi*16+fr; s spans regs r, frags fs, quarters)
#pragma unroll
        for (int fqi = 0; fqi < 2; ++fqi) {
            float mx = stt[0][fqi][0];
#pragma unroll
            for (int fs = 0; fs < 4; ++fs)
#pragma unroll
                for (int r = 0; r < 4; ++r) mx = fmaxf(mx, stt[fs][fqi][r]);
            mx = fmaxf(mx, __shfl_xor(mx, 16));
            mx = fmaxf(mx, __shfl_xor(mx, 32));
            const float nm = fmaxf(mrun[fqi], mx);
            const float scf = __expf(mrun[fqi] - nm);
            mrun[fqi] = nm;
            float ps = 0.f;
#pragma unroll
            for (int fs = 0; fs < 4; ++fs)
#pragma unroll
                for (int r = 0; r < 4; ++r) {
                    const float p = __expf(stt[fs][fqi][r] - nm);
                    stt[fs][fqi][r] = p;
                    ps += p;
                }
            ps += __shfl_xor(ps, 16);
            ps += __shfl_xor(ps, 32);
            lrun[fqi] = lrun[fqi] * scf + ps;
            if (fq4 == 0) sSc[w * 32 + fqi * 16 + fr] = scf;
        }

        // ---- write P[q][s] hi/lo (b64 packs of 4 consecutive s)
#pragma unroll
        for (int fqi = 0; fqi < 2; ++fqi)
#pragma unroll
            for (int fs = 0; fs < 4; ++fs) {
                const int q = w * 32 + fqi * 16 + fr;
                const int flog = (fs << 1) | (fq4 >> 1);
                const int off = q * 128 + ((flog ^ (q & 7)) << 4) + ((fq4 & 1) << 3);
                uint2 hp, lp;
                split_pack4(stt[fs][fqi][0], stt[fs][fqi][1],
                            stt[fs][fqi][2], stt[fs][fqi][3], hp, lp);
                *(uint2*)((char*)sPh + off) = hp;
                *(uint2*)((char*)sPl + off) = lp;
            }

        // ---- rescale oacc (q per PV layout = fqi*16 + fq4*4 + r)
#pragma unroll
        for (int fqi = 0; fqi < 2; ++fqi)
#pragma unroll
            for (int r = 0; r < 4; ++r) {
                const float scv = sSc[w * 32 + fqi * 16 + fq4 * 4 + r];
#pragma unroll
                for (int fd = 0; fd < 4; ++fd) oacc[fqi][fd][r] *= scv;
            }

        // ---- PV: oacc[fq][fd] += P x V   (P wave-private; Vt staged)
#pragma unroll
        for (int ks = 0; ks < 2; ++ks) {
            short8 pfh[2], pfl[2], vfh[4], vfl[4];
#pragma unroll
            for (int fqi = 0; fqi < 2; ++fqi) {
                const int row = w * 32 + fqi * 16 + fr;
                const int off = row * 128 + (((ks * 4 + fq4) ^ (row & 7)) << 4);
                pfh[fqi] = *(const short8*)((const char*)sPh + off);
                pfl[fqi] = *(const short8*)((const char*)sPl + off);
            }
#pragma unroll
            for (int fd = 0; fd < 4; ++fd) {
                const int row = fd * 16 + fr;
                const int off = row * 128 + (((ks * 4 + fq4) ^ (row & 7)) << 4);
                vfh[fd] = *(const short8*)((const char*)sVh + off);
                vfl[fd] = *(const short8*)((const char*)sVl + off);
            }
#pragma unroll
            for (int fqi = 0; fqi < 2; ++fqi)
#pragma unroll
                for (int fd = 0; fd < 4; ++fd) {
                    oacc[fqi][fd] = __builtin_amdgcn_mfma_f32_16x16x32_bf16(pfh[fqi], vfh[fd], oacc[fqi][fd], 0, 0, 0);
                    oacc[fqi][fd] = __builtin_amdgcn_mfma_f32_16x16x32_bf16(pfh[fqi], vfl[fd], oacc[fqi][fd], 0, 0, 0);
                    oacc[fqi][fd] = __builtin_amdgcn_mfma_f32_16x16x32_bf16(pfl[fqi], vfh[fd], oacc[fqi][fd], 0, 0, 0);
                }
        }
    }

    // ---- normalize + store (broadcast lrun across quarters via sSc; wave-private)
    if (fq4 == 0) {
        sSc[w * 32 + fr] = lrun[0];
        sSc[w * 32 + 16 + fr] = lrun[1];
    }
#pragma unroll
    for (int fqi = 0; fqi < 2; ++fqi)
#pragma unroll
        for (int r = 0; r < 4; ++r) {
            const float inv = 1.0f / sSc[w * 32 + fqi * 16 + fq4 * 4 + r];
            const int q = w * 32 + fqi * 16 + fq4 * 4 + r;
#pragma unroll
            for (int fd = 0; fd < 4; ++fd)
                Og[(size_t)q * HH + fd * 16 + fr] = oacc[fqi][fd][r] * inv;
        }
}

// imp[row] = sigmoid(dot(h1[row,0:256], Wi2) + bi2); one wave per row
__global__ __launch_bounds__(256) void imp_kernel(
    const float* __restrict__ h1, const float* __restrict__ Wi2,
    const float* __restrict__ bi2, float* __restrict__ imp)
{
    const int wv = threadIdx.x >> 6, lane = threadIdx.x & 63;
    const int row = blockIdx.x * 4 + wv;
    const float4 hv = *(const float4*)(h1 + (size_t)row * 256 + lane * 4);
    const float4 wvv = *(const float4*)(Wi2 + lane * 4);
    float s = hv.x * wvv.x + hv.y * wvv.y + hv.z * wvv.z + hv.w * wvv.w;
#pragma unroll
    for (int m = 1; m < 64; m <<= 1) s += __shfl_xor(s, m);
    if (lane == 0) imp[row] = 1.0f / (1.0f + expf(-(s + bi2[0])));
}

// per batch: mean(imp), last index with imp>0.5, exists
__global__ __launch_bounds__(256) void impstats_kernel(
    const float* __restrict__ imp, float* __restrict__ imp_mean,
    int* __restrict__ s_star, int* __restrict__ exists)
{
    const int b = blockIdx.x, tid = threadIdx.x;
    float sum = 0.f; int last = -1;
    for (int s = tid; s < SS; s += 256) {
        const float v = imp[b * SS + s];
        sum += v;
        if (v > 0.5f) last = s;
    }
#pragma unroll
    for (int m = 1; m < 64; m <<= 1) {
        sum += __shfl_xor(sum, m);
        last = max(last, __shfl_xor(last, m));
    }
    __shared__ float ssum[4]; __shared__ int slast[4];
    if ((tid & 63) == 0) { ssum[tid >> 6] = sum; slast[tid >> 6] = last; }
    __syncthreads();
    if (tid == 0) {
        const float t = ssum[0] + ssum[1] + ssum[2] + ssum[3];
        const int ml = max(max(slast[0], slast[1]), max(slast[2], slast[3]));
        imp_mean[b] = t / (float)SS;
        exists[b] = (ml >= 0) ? 1 : 0;
        s_star[b] = (ml >= 0) ? ml : (SS - 1);
    }
}

// rowmean over H of write_weights; one wave per row
__global__ __launch_bounds__(256) void rowmean_kernel(
    const float* __restrict__ ww, float* __restrict__ rm)
{
    const int wv = threadIdx.x >> 6, lane = threadIdx.x & 63;
    const int row = blockIdx.x * 4 + wv;
    const float* p = ww + (size_t)row * HH + lane * 8;
    const float4 v0 = *(const float4*)p;
    const float4 v1 = *(const float4*)(p + 4);
    float s = v0.x + v0.y + v0.z + v0.w + v1.x + v1.y + v1.z + v1.w;
#pragma unroll
    for (int m = 1; m < 64; m <<= 1) s += __shfl_xor(s, m);
    if (lane == 0) rm[row] = s * (1.0f / (float)HH);
}

// per batch: first-occurrence argmax over M rowmeans
__global__ __launch_bounds__(256) void argmax_kernel(
    const float* __restrict__ rm, int* __restrict__ pos)
{
    const int b = blockIdx.x, tid = threadIdx.x;
    float best = -3.0e38f; int bidx = 1 << 30;
    for (int m = tid; m < MM; m += 256) {
        const float v = rm[b * MM + m];
        if (v > best || (v == best && m < bidx)) { best = v; bidx = m; }
    }
#pragma unroll
    for (int msk = 1; msk < 64; msk <<= 1) {
        const float ov = __shfl_xor(best, msk);
        const int oi = __shfl_xor(bidx, msk);
        if (ov > best || (ov == best && oi < bidx)) { best = ov; bidx = oi; }
    }
    __shared__ float sv[4]; __shared__ int si[4];
    if ((tid & 63) == 0) { sv[tid >> 6] = best; si[tid >> 6] = bidx; }
    __syncthreads();
    if (tid == 0) {
        for (int w = 1; w < 4; ++w)
            if (sv[w] > best || (sv[w] == best && si[w] < bidx)) { best = sv[w]; bidx = si[w]; }
        pos[b] = bidx;
    }
}

// per batch: upd = tanh(relu([old,sel]@Wu1+bu1)@Wu2+bu2); write updated row
__global__ __launch_bounds__(256) void update_kernel(
    const float* __restrict__ mb, const float* __restrict__ ni,
    const float* __restrict__ Wu1, const float* __restrict__ bu1,
    const float* __restrict__ Wu2, const float* __restrict__ bu2,
    const float* __restrict__ wwp, const int* __restrict__ pos,
    const int* __restrict__ s_star, const int* __restrict__ exists,
    float* __restrict__ outu)
{
    const int b = blockIdx.x, tid = threadIdx.x;
    __shared__ float comb[2 * DD];
    __shared__ float hu[HH];
    const int p = pos[b], ss = s_star[b], ex = exists[b];
    const float* oldp = mb + ((size_t)(b * MM + p)) * DD;
    const float* selp = ni + ((size_t)(b * SS + ss)) * DD;
    for (int i = tid; i < DD; i += 256) { comb[i] = oldp[i]; comb[DD + i] = selp[i]; }
    __syncthreads();
#pragma unroll
    for (int t = 0; t < 2; ++t) {
        const int n = tid + t * 256;
        float a = bu1[n];
        for (int k = 0; k < 2 * DD; ++k) a = fmaf(comb[k], Wu1[(size_t)k * HH + n], a);
        hu[n] = fmaxf(a, 0.f);
    }
    __syncthreads();
#pragma unroll
    for (int t = 0; t < 2; ++t) {
        const int n = tid + t * 256;
        float a = bu2[n];
        for (int k = 0; k < HH; ++k) a = fmaf(hu[k], Wu2[(size_t)k * HH + n], a);
        const float upd = tanhf(a);
        const float wwv = wwp[((size_t)(b * MM + p)) * HH + n];
        const float ov = oldp[n];
        outu[((size_t)(b * MM + p)) * DD + n] = ex ? fmaf(upd, wwv, ov) : ov;
    }
}

extern "C" void kernel_launch(void* const* d_in, const int* in_sizes, int n_in,
                              void* d_out, int out_size, void* d_ws, size_t ws_size,
                              hipStream_t stream)
{
    const float* new_info    = (const float*)d_in[0];
    const float* memory_bank = (const float*)d_in[1];
    const float* W_in = (const float*)d_in[2];  const float* b_in = (const float*)d_in[3];
    const float* Wq   = (const float*)d_in[4];  const float* bq   = (const float*)d_in[5];
    const float* Wk   = (const float*)d_in[6];  const float* bk   = (const float*)d_in[7];
    const float* Wv   = (const float*)d_in[8];  const float* bv   = (const float*)d_in[9];
    const float* Wo   = (const float*)d_in[10]; const float* bo   = (const float*)d_in[11];
    const float* Wi1  = (const float*)d_in[12]; const float* bi1  = (const float*)d_in[13];
    const float* Wi2  = (const float*)d_in[14]; const float* bi2  = (const float*)d_in[15];
    const float* Wu1  = (const float*)d_in[16]; const float* bu1  = (const float*)d_in[17];
    const float* Wu2  = (const float*)d_in[18]; const float* bu2  = (const float*)d_in[19];

    float* out = (float*)d_out;
    float* out_updated = out;                               // B*M*D
    float* out_ww      = out + (size_t)BB * MM * HH;        // B*M*H
    float* out_imp     = out + 2 * (size_t)BB * MM * HH;    // B*S

    // workspace layout (f32 units), ~123 MB
    float* ws = (float*)d_ws;
    float* info_proj = ws;                                  // 4,194,304
    float* khb       = info_proj + 4194304;                 // 4,194,304
    float* vhb       = khb + 4194304;                       // 4,194,304
    float* qhb       = vhb + 4194304;                       // 8,388,608 (hidden1 aliases)
    float* mem_proj  = qhb + 8388608;                       // 8,388,608
    float* wt_region = mem_proj + 8388608;                  // 1,310,720 (10 x 262,144 u16)
    float* rowmeanv  = wt_region + 1310720;                 // 16,384
    float* imp_mean  = rowmeanv + 16384;                    // 8
    int*   ipos      = (int*)(imp_mean + BB);
    int*   istar     = ipos + BB;
    int*   iexists   = istar + BB;

    float* hidden1 = qhb;  // B*S*256, dead before Q-GEMM writes qhb

    us* wtin_h = (us*)wt_region;
    us* wtin_l = wtin_h + 262144;
    us* wtq_h  = wtin_l + 262144;
    us* wtq_l  = wtq_h + 262144;
    us* wtk_h  = wtq_l + 262144;
    us* wtk_l  = wtk_h + 262144;
    us* wtv_h  = wtk_l + 262144;
    us* wtv_l  = wtv_h + 262144;
    us* wto_h  = wtv_l + 262144;
    us* wto_l  = wto_h + 262144;

    const dim3 blk(256);

    hipMemcpyAsync(out_updated, memory_bank,
                   (size_t)BB * MM * DD * sizeof(float),
                   hipMemcpyDeviceToDevice, stream);

    // ---- weight prep: transpose+split all 5 projection weights in one launch
    TS5 ts;
    ts.src[0] = W_in; ts.dh[0] = wtin_h; ts.dl[0] = wtin_l;
    ts.src[1] = Wq;   ts.dh[1] = wtq_h;  ts.dl[1] = wtq_l;
    ts.src[2] = Wk;   ts.dh[2] = wtk_h;  ts.dl[2] = wtk_l;
    ts.src[3] = Wv;   ts.dh[3] = wtv_h;  ts.dl[3] = wtv_l;
    ts.src[4] = Wo;   ts.dh[4] = wto_h;  ts.dl[4] = wto_l;
    transpose_split_batch<<<dim3(16, 16, 5), blk, 0, stream>>>(ts);

    // ---- importance path stays exact f32 (imp sits ~1e-6 from 0.5 threshold)
    gemm128<<<dim3(4, 64), blk, 0, stream>>>(new_info, W_in, b_in, info_proj,
                                             DD, HH, 0, nullptr, 1);
    gemm128<<<dim3(2, 64), blk, 0, stream>>>(info_proj, Wi1, bi1, hidden1,
                                             HH, HH / 2, 1, nullptr, 1);
    imp_kernel<<<dim3((BB * SS) / 4), blk, 0, stream>>>(hidden1, Wi2, bi2, out_imp);
    impstats_kernel<<<dim3(BB), blk, 0, stream>>>(out_imp, imp_mean, istar, iexists);

    // ---- MFMA GEMMs (f32 A, split in-kernel)
    gemm_mfma<<<dim3(4, 128), blk, 0, stream>>>(memory_bank, wtin_h, wtin_l,
                                                b_in, mem_proj, 512, 512, nullptr, 1);
    gemm_mfma<<<dim3(4, 128), blk, 0, stream>>>(mem_proj, wtq_h, wtq_l,
                                                bq, qhb, 512, 512, nullptr, 1);
    gemm_mfma<<<dim3(4, 64), blk, 0, stream>>>(info_proj, wtk_h, wtk_l,
                                               bk, khb, 512, 512, nullptr, 1);
    gemm_mfma<<<dim3(4, 64), blk, 0, stream>>>(info_proj, wtv_h, wtv_l,
                                               bv, vhb, 512, 512, nullptr, 1);

    // ---- MFMA flash attention (writes back into qhb; each block owns its rows)
    attn_mfma<<<dim3(1024), blk, 0, stream>>>(qhb, khb, vhb, qhb);

    // ---- output projection (+ imp_mean rowscale) -> write_weights
    gemm_mfma<<<dim3(4, 128), blk, 0, stream>>>(qhb, wto_h, wto_l,
                                                bo, out_ww, 512, 512, imp_mean, MM);

    // ---- slot selection + final row update
    rowmean_kernel<<<dim3((BB * MM) / 4), blk, 0, stream>>>(out_ww, rowmeanv);
    argmax_kernel<<<dim3(BB), blk, 0, stream>>>(rowmeanv, ipos);
    update_kernel<<<dim3(BB), blk, 0, stream>>>(memory_bank, new_info,
                                                Wu1, bu1, Wu2, bu2, out_ww,
                                                ipos, istar, iexists, out_updated);
}